// Round 2
// baseline (219.726 us; speedup 1.0000x reference)
//
#include <hip/hip_runtime.h>
#include <hip/hip_bf16.h>

typedef unsigned short u16;
typedef unsigned int   u32;
typedef u32 __attribute__((address_space(1))) gas_u32;
typedef u32 __attribute__((address_space(3))) las_u32;
typedef __bf16 bf16x8 __attribute__((ext_vector_type(8)));
typedef float  f32x4  __attribute__((ext_vector_type(4)));

constexpr int BATCH = 4, SEQ = 4096, HID = 1024, NH = 16, DH = 64;
constexpr int M  = BATCH * SEQ;   // 16384 rows
constexpr int KD = HID;           // 1024 (K of all GEMMs)

__device__ __forceinline__ u16 f2bf(float f) {
  __hip_bfloat16 h = __float2bfloat16(f);
  u16 u; __builtin_memcpy(&u, &h, 2); return u;
}
__device__ __forceinline__ float bf2f(u16 u) {
  u32 x = ((u32)u) << 16; float f; __builtin_memcpy(&f, &x, 4); return f;
}

// ---------------- prep kernels ----------------

// x (fp32) -> xb (bf16), 8 elems/thread, exact grid
__global__ __launch_bounds__(256) void cast_x_kernel(const float4* __restrict__ x,
                                                     uint4* __restrict__ xb) {
  int i = blockIdx.x * 256 + threadIdx.x;      // 2,097,152 threads
  float4 a = x[2 * i], b = x[2 * i + 1];
  uint4 o;
  o.x = (u32)f2bf(a.x) | ((u32)f2bf(a.y) << 16);
  o.y = (u32)f2bf(a.z) | ((u32)f2bf(a.w) << 16);
  o.z = (u32)f2bf(b.x) | ((u32)f2bf(b.y) << 16);
  o.w = (u32)f2bf(b.z) | ((u32)f2bf(b.w) << 16);
  xb[i] = o;
}

// Wk, Wo (K x N fp32) -> WkT, WoT (N x K bf16)
__global__ __launch_bounds__(256) void transpose_cast(const float* __restrict__ Wk,
                                                      const float* __restrict__ Wo,
                                                      u16* __restrict__ WkT,
                                                      u16* __restrict__ WoT) {
  __shared__ float tile[32][33];
  const float* src = blockIdx.z ? Wo : Wk;
  u16* dst = blockIdx.z ? WoT : WkT;
  int bx = blockIdx.x * 32, by = blockIdx.y * 32;
  int tx = threadIdx.x & 31, ty = threadIdx.x >> 5;   // 32 x 8
#pragma unroll
  for (int i = 0; i < 4; i++)
    tile[ty + i * 8][tx] = src[(size_t)(by + ty + i * 8) * HID + bx + tx];
  __syncthreads();
#pragma unroll
  for (int i = 0; i < 4; i++)
    dst[(size_t)(bx + ty + i * 8) * HID + by + tx] = f2bf(tile[tx][ty + i * 8]);
}

// WsumT (64 x 1024 bf16, row-major N x K): cols 0..15 = colsum(Wq) per head,
// 16..31 = colsum(Wv), 32..47 = Wbeta, 48..63 = zero padding
__global__ __launch_bounds__(256) void build_wsum(const float* __restrict__ Wq,
                                                  const float* __restrict__ Wv,
                                                  const float* __restrict__ Wbeta,
                                                  u16* __restrict__ WsT) {
  int tid = blockIdx.x * 256 + threadIdx.x;   // 65536
  int c = tid >> 10, kk = tid & 1023;
  float s = 0.f;
  if (c < 16)      { for (int d = 0; d < DH; d++) s += Wq[(size_t)kk * HID + c * DH + d]; }
  else if (c < 32) { for (int d = 0; d < DH; d++) s += Wv[(size_t)kk * HID + (c - 16) * DH + d]; }
  else if (c < 48) { s = Wbeta[(size_t)kk * NH + (c - 32)]; }
  WsT[(size_t)c * HID + kk] = f2bf(s);
}

// ---------------- bf16 MFMA GEMM (m97 structure + T1 XCD swizzle) ----------------
// C(MxN) = A(MxK) * Bt(NxK)^T ; BK=64, 256 threads = 4 waves.
// EPI 0: store bf16 C.  EPI 1: skinny head-stat epilogue (transposed [seq][t]
// layout, sigmoid on beta cols).  EPI 2: y = bf16(xres_bf16 + C + b_o), may be
// in-place with xres (same-thread read-then-write; no __restrict__ on those).
template <int BM, int BN, int WGM, int WGN, int EPI>
__global__ __launch_bounds__(256) void gemm_bf16(
    const u16* __restrict__ A, const u16* __restrict__ Bt, int N, int K,
    u16* Cb, const u16* xres,
    const float* __restrict__ bias, float* __restrict__ sq,
    float* __restrict__ sv, float* __restrict__ sb) {
  constexpr int BK = 64;
  constexpr int WTM = BM / WGM, WTN = BN / WGN, FM = WTM / 16, FN = WTN / 16;
  __shared__ u16 As[BM * BK];
  __shared__ u16 Bs[BN * BK];
  const int tid = threadIdx.x, wave = tid >> 6, lane = tid & 63;
  const int nbn = N / BN;
  // T1: bijective XCD swizzle (grid % 8 == 0 for all our launches).
  // Blocks sharing an A-panel (consecutive bn) land on the same XCD's L2.
  const int nwg = (int)gridDim.x;
  const int q8 = nwg >> 3;
  const int swz = ((int)blockIdx.x & 7) * q8 + ((int)blockIdx.x >> 3);
  const int bm = swz / nbn, bn = swz % nbn;
  const int wm = wave / WGN, wn = wave % WGN;
  const int r16 = lane & 15, hi = lane >> 4;
  const int rsub = lane >> 3, csub = (lane & 7) * 8;

  f32x4 acc[FM][FN] = {};

  const u16* Ab = A + (size_t)bm * BM * K;
  const u16* Bb = Bt + (size_t)bn * BN * K;

  for (int kt = 0; kt < K; kt += BK) {
    {  // stage A and B tiles: linear LDS, wave-uniform base + lane*16B
      constexpr int PWA = BM / 32;
#pragma unroll
      for (int i = 0; i < PWA; i++) {
        int slot = wave * PWA + i;
        const u16* g = Ab + (size_t)(slot * 8 + rsub) * K + kt + csub;
        __builtin_amdgcn_global_load_lds((gas_u32*)g, (las_u32*)(As + slot * 512), 16, 0, 0);
      }
      constexpr int PWB = BN / 32;
#pragma unroll
      for (int i = 0; i < PWB; i++) {
        int slot = wave * PWB + i;
        const u16* g = Bb + (size_t)(slot * 8 + rsub) * K + kt + csub;
        __builtin_amdgcn_global_load_lds((gas_u32*)g, (las_u32*)(Bs + slot * 512), 16, 0, 0);
      }
    }
    __syncthreads();  // compiler drains vmcnt(0) before s_barrier
#pragma unroll
    for (int kk = 0; kk < BK / 32; kk++) {
      bf16x8 af[FM], bfr[FN];
#pragma unroll
      for (int f = 0; f < FM; f++)
        af[f] = *(const bf16x8*)(As + (wm * WTM + f * 16 + r16) * BK + kk * 32 + hi * 8);
#pragma unroll
      for (int f = 0; f < FN; f++)
        bfr[f] = *(const bf16x8*)(Bs + (wn * WTN + f * 16 + r16) * BK + kk * 32 + hi * 8);
#pragma unroll
      for (int fm = 0; fm < FM; fm++)
#pragma unroll
        for (int fn = 0; fn < FN; fn++)
          acc[fm][fn] = __builtin_amdgcn_mfma_f32_16x16x32_bf16(af[fm], bfr[fn], acc[fm][fn], 0, 0, 0);
    }
    __syncthreads();
  }

#pragma unroll
  for (int fm = 0; fm < FM; fm++) {
#pragma unroll
    for (int fn = 0; fn < FN; fn++) {
      const int col = bn * BN + wn * WTN + fn * 16 + r16;
#pragma unroll
      for (int j = 0; j < 4; j++) {
        const int row = bm * BM + wm * WTM + fm * 16 + hi * 4 + j;
        float v = acc[fm][fn][j];
        if constexpr (EPI == 0) {
          Cb[(size_t)row * N + col] = f2bf(v);
        } else if constexpr (EPI == 1) {
          const int b = row >> 12, t = row & 4095;
          if (col < 16)      sq[((size_t)(b * 16 + col)) * SEQ + t] = v;
          else if (col < 32) sv[((size_t)(b * 16 + col - 16)) * SEQ + t] = v;
          else if (col < 48) {
            float z = v + bias[col - 32];
            sb[((size_t)(b * 16 + col - 32)) * SEQ + t] = 1.f / (1.f + __expf(-z));
          }
        } else {
          float y = bf2f(xres[(size_t)row * N + col]) + v + bias[col];
          Cb[(size_t)row * N + col] = f2bf(y);
        }
      }
    }
  }
}

// ---------------- chunked scan: r_t = b_t*r_{t-1} + k_t*vsum_t ----------------
// 64 sequences (b,head) x 64 chunks of 64 steps. lane = d.

__global__ __launch_bounds__(256) void scan_chunks(const u16* __restrict__ kbuf,
                                                   const float* __restrict__ sv_t,
                                                   const float* __restrict__ sb_t,
                                                   float* __restrict__ Pbuf,
                                                   float* __restrict__ Rloc) {
  const int wave = threadIdx.x >> 6, lane = threadIdx.x & 63;
  const int gid = blockIdx.x * 4 + wave;       // [0, 4096)
  const int seq = gid >> 6, chunk = gid & 63;
  const int b = seq >> 4, h = seq & 15;
  const int t0 = chunk * 64;
  const float bet = sb_t[(size_t)seq * SEQ + t0 + lane];
  const float vs  = sv_t[(size_t)seq * SEQ + t0 + lane];
  const u16* kp = kbuf + ((size_t)(b * SEQ + t0)) * HID + h * DH + lane;
  float r = 0.f, P = 1.f;
#pragma unroll
  for (int tt = 0; tt < 64; tt += 8) {
    u16 kr[8];
#pragma unroll
    for (int j = 0; j < 8; j++) kr[j] = kp[(size_t)(tt + j) * HID];
#pragma unroll
    for (int j = 0; j < 8; j++) {
      float bt = __shfl(bet, tt + j);
      float vt = __shfl(vs, tt + j);
      r = fmaf(r, bt, bf2f(kr[j]) * vt);
      P *= bt;
    }
  }
  Rloc[(size_t)gid * 64 + lane] = r;
  if (lane == 0) Pbuf[gid] = P;
}

__global__ __launch_bounds__(64) void scan_prefix(const float* __restrict__ Pbuf,
                                                  const float* __restrict__ Rloc,
                                                  float* __restrict__ Rin) {
  const int seq = blockIdx.x, lane = threadIdx.x;
  const float* pp = Pbuf + seq * 64;
  const float* rl = Rloc + (size_t)seq * 64 * 64 + lane;
  float* ri = Rin + (size_t)seq * 64 * 64 + lane;
  float rin = 0.f;
#pragma unroll
  for (int c0 = 0; c0 < 64; c0 += 8) {
    float P[8], L[8];
#pragma unroll
    for (int j = 0; j < 8; j++) { P[j] = pp[c0 + j]; L[j] = rl[(size_t)(c0 + j) * 64]; }
#pragma unroll
    for (int j = 0; j < 8; j++) {
      ri[(size_t)(c0 + j) * 64] = rin;       // state ENTERING chunk c0+j
      rin = fmaf(P[j], rin, L[j]);
    }
  }
}

__global__ __launch_bounds__(256) void scan_apply(const u16* __restrict__ kbuf,
                                                  const float* __restrict__ sq_t,
                                                  const float* __restrict__ sv_t,
                                                  const float* __restrict__ sb_t,
                                                  const float* __restrict__ Rin,
                                                  u16* __restrict__ obuf) {
  const int wave = threadIdx.x >> 6, lane = threadIdx.x & 63;
  const int gid = blockIdx.x * 4 + wave;
  const int seq = gid >> 6, chunk = gid & 63;
  const int b = seq >> 4, h = seq & 15;
  const int t0 = chunk * 64;
  const float bet = sb_t[(size_t)seq * SEQ + t0 + lane];
  const float vs  = sv_t[(size_t)seq * SEQ + t0 + lane];
  const float qs  = sq_t[(size_t)seq * SEQ + t0 + lane];
  const u16* kp = kbuf + ((size_t)(b * SEQ + t0)) * HID + h * DH + lane;
  u16* op = obuf + ((size_t)(b * SEQ + t0)) * HID + h * DH + lane;
  float r = Rin[(size_t)gid * 64 + lane];
#pragma unroll
  for (int tt = 0; tt < 64; tt += 8) {
    u16 kr[8];
#pragma unroll
    for (int j = 0; j < 8; j++) kr[j] = kp[(size_t)(tt + j) * HID];
#pragma unroll
    for (int j = 0; j < 8; j++) {
      float bt = __shfl(bet, tt + j);
      float vt = __shfl(vs, tt + j);
      float qt = __shfl(qs, tt + j);
      r = fmaf(r, bt, bf2f(kr[j]) * vt);
      op[(size_t)(tt + j) * HID] = f2bf(qt * r);
    }
  }
}

// ---------------- LayerNorm (row per block) ----------------
__global__ __launch_bounds__(256) void ln_kernel(const u16* __restrict__ y,
                                                 const float* __restrict__ g,
                                                 const float* __restrict__ bt,
                                                 float* __restrict__ out) {
  const int row = blockIdx.x;
  const u16* yr = y + (size_t)row * HID;
  const int t = threadIdx.x;
  ushort4 u = *(const ushort4*)(yr + t * 4);
  float v0 = bf2f(u.x), v1 = bf2f(u.y), v2 = bf2f(u.z), v3 = bf2f(u.w);
  float s  = v0 + v1 + v2 + v3;
  float ss = v0 * v0 + v1 * v1 + v2 * v2 + v3 * v3;
#pragma unroll
  for (int m = 1; m < 64; m <<= 1) { s += __shfl_xor(s, m); ss += __shfl_xor(ss, m); }
  __shared__ float red[8];
  const int wave = t >> 6, lane = t & 63;
  if (lane == 0) { red[wave] = s; red[4 + wave] = ss; }
  __syncthreads();
  float st  = red[0] + red[1] + red[2] + red[3];
  float sst = red[4] + red[5] + red[6] + red[7];
  float mu  = st * (1.f / 1024.f);
  float var = sst * (1.f / 1024.f) - mu * mu;
  float inv = rsqrtf(var + 1e-5f);
  const int c = t * 4;
  float* o = out + (size_t)row * HID + c;
  o[0] = g[c + 0] * ((v0 - mu) * inv) + bt[c + 0];
  o[1] = g[c + 1] * ((v1 - mu) * inv) + bt[c + 1];
  o[2] = g[c + 2] * ((v2 - mu) * inv) + bt[c + 2];
  o[3] = g[c + 3] * ((v3 - mu) * inv) + bt[c + 3];
}

// ---------------- launch ----------------
extern "C" void kernel_launch(void* const* d_in, const int* in_sizes, int n_in,
                              void* d_out, int out_size, void* d_ws, size_t ws_size,
                              hipStream_t stream) {
  const float* x     = (const float*)d_in[0];
  const float* Wq    = (const float*)d_in[1];
  const float* Wk    = (const float*)d_in[2];
  const float* Wv    = (const float*)d_in[3];
  const float* Wbeta = (const float*)d_in[4];
  const float* bbeta = (const float*)d_in[5];
  const float* Wo    = (const float*)d_in[6];
  const float* b_o   = (const float*)d_in[7];
  const float* ln_g  = (const float*)d_in[8];
  const float* ln_b  = (const float*)d_in[9];
  float* out = (float*)d_out;

  char* ws = (char*)d_ws;
  size_t off = 0;
  auto alloc = [&](size_t bytes) {
    char* p = ws + off; off += (bytes + 255) & ~(size_t)255; return p;
  };
  u16* xb   = (u16*)alloc((size_t)M * HID * 2);   // x bf16; later reused as y
  u16* kbuf = (u16*)alloc((size_t)M * HID * 2);
  u16* obuf = (u16*)alloc((size_t)M * HID * 2);
  u16* WkT  = (u16*)alloc((size_t)HID * HID * 2);
  u16* WoT  = (u16*)alloc((size_t)HID * HID * 2);
  u16* WsT  = (u16*)alloc((size_t)64 * HID * 2);
  float* sq_t = (float*)alloc((size_t)64 * SEQ * 4);
  float* sv_t = (float*)alloc((size_t)64 * SEQ * 4);
  float* sb_t = (float*)alloc((size_t)64 * SEQ * 4);
  float* Pbuf = (float*)alloc((size_t)4096 * 4);
  float* Rloc = (float*)alloc((size_t)4096 * 64 * 4);
  float* Rin  = (float*)alloc((size_t)4096 * 64 * 4);
  u16* ybuf = xb;  // alias: xb dead (as x) after EPI2 consumes it as residual

  cast_x_kernel<<<8192, 256, 0, stream>>>((const float4*)x, (uint4*)xb);
  transpose_cast<<<dim3(32, 32, 2), 256, 0, stream>>>(Wk, Wo, WkT, WoT);
  build_wsum<<<256, 256, 0, stream>>>(Wq, Wv, Wbeta, WsT);

  gemm_bf16<128, 128, 2, 2, 0><<<(M / 128) * (HID / 128), 256, 0, stream>>>(
      xb, WkT, HID, KD, kbuf, nullptr, nullptr, nullptr, nullptr, nullptr);
  gemm_bf16<128, 64, 4, 1, 1><<<(M / 128), 256, 0, stream>>>(
      xb, WsT, 64, KD, nullptr, nullptr, bbeta, sq_t, sv_t, sb_t);

  scan_chunks<<<1024, 256, 0, stream>>>(kbuf, sv_t, sb_t, Pbuf, Rloc);
  scan_prefix<<<64, 64, 0, stream>>>(Pbuf, Rloc, Rin);
  scan_apply<<<1024, 256, 0, stream>>>(kbuf, sq_t, sv_t, sb_t, Rin, obuf);

  // EPI2: residual read from xb (bf16), output written in-place over xb (=ybuf)
  gemm_bf16<128, 128, 2, 2, 2><<<(M / 128) * (HID / 128), 256, 0, stream>>>(
      obuf, WoT, HID, KD, ybuf, xb, b_o, nullptr, nullptr, nullptr);

  ln_kernel<<<M, 256, 0, stream>>>(ybuf, ln_g, ln_b, out);
}

// Round 3
// 205.040 us; speedup vs baseline: 1.0716x; 1.0716x over previous
//
#include <hip/hip_runtime.h>
#include <hip/hip_bf16.h>

typedef unsigned short u16;
typedef unsigned int   u32;
typedef u32 __attribute__((address_space(1))) gas_u32;
typedef u32 __attribute__((address_space(3))) las_u32;
typedef __bf16 bf16x8 __attribute__((ext_vector_type(8)));
typedef float  f32x4  __attribute__((ext_vector_type(4)));

constexpr int BATCH = 4, SEQ = 4096, HID = 1024, NH = 16, DH = 64;
constexpr int M  = BATCH * SEQ;   // 16384 rows
constexpr int KD = HID;           // 1024 (K of all GEMMs)

__device__ __forceinline__ u16 f2bf(float f) {
  __hip_bfloat16 h = __float2bfloat16(f);
  u16 u; __builtin_memcpy(&u, &h, 2); return u;
}
__device__ __forceinline__ float bf2f(u16 u) {
  u32 x = ((u32)u) << 16; float f; __builtin_memcpy(&f, &x, 4); return f;
}

// ---------------- prep kernels ----------------

// x (fp32) -> xb (bf16), 8 elems/thread, exact grid
__global__ __launch_bounds__(256) void cast_x_kernel(const float4* __restrict__ x,
                                                     uint4* __restrict__ xb) {
  int i = blockIdx.x * 256 + threadIdx.x;      // 2,097,152 threads
  float4 a = x[2 * i], b = x[2 * i + 1];
  uint4 o;
  o.x = (u32)f2bf(a.x) | ((u32)f2bf(a.y) << 16);
  o.y = (u32)f2bf(a.z) | ((u32)f2bf(a.w) << 16);
  o.z = (u32)f2bf(b.x) | ((u32)f2bf(b.y) << 16);
  o.w = (u32)f2bf(b.z) | ((u32)f2bf(b.w) << 16);
  xb[i] = o;
}

// Wk, Wo (K x N fp32) -> WkT, WoT (N x K bf16)
__global__ __launch_bounds__(256) void transpose_cast(const float* __restrict__ Wk,
                                                      const float* __restrict__ Wo,
                                                      u16* __restrict__ WkT,
                                                      u16* __restrict__ WoT) {
  __shared__ float tile[32][33];
  const float* src = blockIdx.z ? Wo : Wk;
  u16* dst = blockIdx.z ? WoT : WkT;
  int bx = blockIdx.x * 32, by = blockIdx.y * 32;
  int tx = threadIdx.x & 31, ty = threadIdx.x >> 5;   // 32 x 8
#pragma unroll
  for (int i = 0; i < 4; i++)
    tile[ty + i * 8][tx] = src[(size_t)(by + ty + i * 8) * HID + bx + tx];
  __syncthreads();
#pragma unroll
  for (int i = 0; i < 4; i++)
    dst[(size_t)(bx + ty + i * 8) * HID + by + tx] = f2bf(tile[tx][ty + i * 8]);
}

// WsT (128 x 1024 bf16, row-major N x K): rows 0..15 = colsum(Wq) per head,
// 16..31 = colsum(Wv), 32..47 = Wbeta, 48..127 = zero (padding for BN=128 tile)
__global__ __launch_bounds__(256) void build_wsum(const float* __restrict__ Wq,
                                                  const float* __restrict__ Wv,
                                                  const float* __restrict__ Wbeta,
                                                  u16* __restrict__ WsT) {
  int tid = blockIdx.x * 256 + threadIdx.x;   // 131072
  int c = tid >> 10, kk = tid & 1023;
  float s = 0.f;
  if (c < 16)      { for (int d = 0; d < DH; d++) s += Wq[(size_t)kk * HID + c * DH + d]; }
  else if (c < 32) { for (int d = 0; d < DH; d++) s += Wv[(size_t)kk * HID + (c - 16) * DH + d]; }
  else if (c < 48) { s = Wbeta[(size_t)kk * NH + (c - 32)]; }
  WsT[(size_t)c * HID + kk] = f2bf(s);
}

// ---------------- bf16 MFMA GEMM (m97 structure + T1 XCD swizzle) ----------------
// C(MxN) = A(MxK) * Bt(NxK)^T ; BK=64, 256 threads = 4 waves.
// EPI 0: store bf16 C.
// EPI 2: y = bf16(xres + C + bias) to Cb (Cb != xres, both restrict).
// EPI 3: merged: blocks bn < nbn-1 behave like EPI 0 on Bt; block bn == nbn-1
//        uses Bt2 (WsT) and runs the skinny head-stat epilogue (sigmoid beta).
template <int BM, int BN, int WGM, int WGN, int EPI>
__global__ __launch_bounds__(256) void gemm_bf16(
    const u16* __restrict__ A, const u16* __restrict__ Bt,
    const u16* __restrict__ Bt2, int N, int K, int nbn,
    u16* __restrict__ Cb, const u16* __restrict__ xres,
    const float* __restrict__ bias, float* __restrict__ sq,
    float* __restrict__ sv, float* __restrict__ sb) {
  constexpr int BK = 64;
  constexpr int WTM = BM / WGM, WTN = BN / WGN, FM = WTM / 16, FN = WTN / 16;
  __shared__ u16 As[BM * BK];
  __shared__ u16 Bs[BN * BK];
  const int tid = threadIdx.x, wave = tid >> 6, lane = tid & 63;
  // T1: bijective XCD swizzle (grid % 8 == 0 for all our launches).
  // Blocks sharing an A-panel (consecutive bn) land on the same XCD's L2.
  const int nwg = (int)gridDim.x;
  const int q8 = nwg >> 3;
  const int swz = ((int)blockIdx.x & 7) * q8 + ((int)blockIdx.x >> 3);
  const int bm = swz / nbn, bn = swz % nbn;
  const int wm = wave / WGN, wn = wave % WGN;
  const int r16 = lane & 15, hi = lane >> 4;
  const int rsub = lane >> 3, csub = (lane & 7) * 8;

  bool skinny = false;
  const u16* Bbase = Bt;
  if constexpr (EPI == 3) {
    skinny = (bn == nbn - 1);
    if (skinny) Bbase = Bt2;
  }

  f32x4 acc[FM][FN] = {};

  const u16* Ab = A + (size_t)bm * BM * K;
  const u16* Bb = skinny ? Bbase : Bbase + (size_t)bn * BN * K;

  for (int kt = 0; kt < K; kt += BK) {
    {  // stage A and B tiles: linear LDS, wave-uniform base + lane*16B
      constexpr int PWA = BM / 32;
#pragma unroll
      for (int i = 0; i < PWA; i++) {
        int slot = wave * PWA + i;
        const u16* g = Ab + (size_t)(slot * 8 + rsub) * K + kt + csub;
        __builtin_amdgcn_global_load_lds((gas_u32*)g, (las_u32*)(As + slot * 512), 16, 0, 0);
      }
      constexpr int PWB = BN / 32;
#pragma unroll
      for (int i = 0; i < PWB; i++) {
        int slot = wave * PWB + i;
        const u16* g = Bb + (size_t)(slot * 8 + rsub) * K + kt + csub;
        __builtin_amdgcn_global_load_lds((gas_u32*)g, (las_u32*)(Bs + slot * 512), 16, 0, 0);
      }
    }
    __syncthreads();  // compiler drains vmcnt(0) before s_barrier
#pragma unroll
    for (int kk = 0; kk < BK / 32; kk++) {
      bf16x8 af[FM], bfr[FN];
#pragma unroll
      for (int f = 0; f < FM; f++)
        af[f] = *(const bf16x8*)(As + (wm * WTM + f * 16 + r16) * BK + kk * 32 + hi * 8);
#pragma unroll
      for (int f = 0; f < FN; f++)
        bfr[f] = *(const bf16x8*)(Bs + (wn * WTN + f * 16 + r16) * BK + kk * 32 + hi * 8);
#pragma unroll
      for (int fm = 0; fm < FM; fm++)
#pragma unroll
        for (int fn = 0; fn < FN; fn++)
          acc[fm][fn] = __builtin_amdgcn_mfma_f32_16x16x32_bf16(af[fm], bfr[fn], acc[fm][fn], 0, 0, 0);
    }
    __syncthreads();
  }

#pragma unroll
  for (int fm = 0; fm < FM; fm++) {
#pragma unroll
    for (int fn = 0; fn < FN; fn++) {
      const int lcol = wn * WTN + fn * 16 + r16;       // col within tile
      const int col = bn * BN + lcol;                  // global col (non-skinny)
#pragma unroll
      for (int j = 0; j < 4; j++) {
        const int row = bm * BM + wm * WTM + fm * 16 + hi * 4 + j;
        float v = acc[fm][fn][j];
        if constexpr (EPI == 2) {
          float y = bf2f(xres[(size_t)row * N + col]) + v + bias[col];
          Cb[(size_t)row * N + col] = f2bf(y);
        } else if constexpr (EPI == 3) {
          if (skinny) {
            const int b = row >> 12, t = row & 4095;
            if (lcol < 16)      sq[((size_t)(b * 16 + lcol)) * SEQ + t] = v;
            else if (lcol < 32) sv[((size_t)(b * 16 + lcol - 16)) * SEQ + t] = v;
            else if (lcol < 48) {
              float z = v + bias[lcol - 32];
              sb[((size_t)(b * 16 + lcol - 32)) * SEQ + t] = 1.f / (1.f + __expf(-z));
            }
          } else {
            Cb[(size_t)row * N + col] = f2bf(v);
          }
        } else {
          Cb[(size_t)row * N + col] = f2bf(v);
        }
      }
    }
  }
}

// ---------------- chunked scan: r_t = b_t*r_{t-1} + k_t*vsum_t ----------------
// 64 sequences (b,head) x 64 chunks of 64 steps. lane = d.

__global__ __launch_bounds__(256) void scan_chunks(const u16* __restrict__ kbuf,
                                                   const float* __restrict__ sv_t,
                                                   const float* __restrict__ sb_t,
                                                   float* __restrict__ Pbuf,
                                                   float* __restrict__ Rloc) {
  const int wave = threadIdx.x >> 6, lane = threadIdx.x & 63;
  const int gid = blockIdx.x * 4 + wave;       // [0, 4096)
  const int seq = gid >> 6, chunk = gid & 63;
  const int b = seq >> 4, h = seq & 15;
  const int t0 = chunk * 64;
  const float bet = sb_t[(size_t)seq * SEQ + t0 + lane];
  const float vs  = sv_t[(size_t)seq * SEQ + t0 + lane];
  const u16* kp = kbuf + ((size_t)(b * SEQ + t0)) * HID + h * DH + lane;
  float r = 0.f, P = 1.f;
#pragma unroll
  for (int tt = 0; tt < 64; tt += 8) {
    u16 kr[8];
#pragma unroll
    for (int j = 0; j < 8; j++) kr[j] = kp[(size_t)(tt + j) * HID];
#pragma unroll
    for (int j = 0; j < 8; j++) {
      float bt = __shfl(bet, tt + j);
      float vt = __shfl(vs, tt + j);
      r = fmaf(r, bt, bf2f(kr[j]) * vt);
      P *= bt;
    }
  }
  Rloc[(size_t)gid * 64 + lane] = r;
  if (lane == 0) Pbuf[gid] = P;
}

__global__ __launch_bounds__(64) void scan_prefix(const float* __restrict__ Pbuf,
                                                  const float* __restrict__ Rloc,
                                                  float* __restrict__ Rin) {
  const int seq = blockIdx.x, lane = threadIdx.x;
  const float* pp = Pbuf + seq * 64;
  const float* rl = Rloc + (size_t)seq * 64 * 64 + lane;
  float* ri = Rin + (size_t)seq * 64 * 64 + lane;
  float rin = 0.f;
#pragma unroll
  for (int c0 = 0; c0 < 64; c0 += 8) {
    float P[8], L[8];
#pragma unroll
    for (int j = 0; j < 8; j++) { P[j] = pp[c0 + j]; L[j] = rl[(size_t)(c0 + j) * 64]; }
#pragma unroll
    for (int j = 0; j < 8; j++) {
      ri[(size_t)(c0 + j) * 64] = rin;       // state ENTERING chunk c0+j
      rin = fmaf(P[j], rin, L[j]);
    }
  }
}

__global__ __launch_bounds__(256) void scan_apply(const u16* __restrict__ kbuf,
                                                  const float* __restrict__ sq_t,
                                                  const float* __restrict__ sv_t,
                                                  const float* __restrict__ sb_t,
                                                  const float* __restrict__ Rin,
                                                  u16* __restrict__ obuf) {
  const int wave = threadIdx.x >> 6, lane = threadIdx.x & 63;
  const int gid = blockIdx.x * 4 + wave;
  const int seq = gid >> 6, chunk = gid & 63;
  const int b = seq >> 4, h = seq & 15;
  const int t0 = chunk * 64;
  const float bet = sb_t[(size_t)seq * SEQ + t0 + lane];
  const float vs  = sv_t[(size_t)seq * SEQ + t0 + lane];
  const float qs  = sq_t[(size_t)seq * SEQ + t0 + lane];
  const u16* kp = kbuf + ((size_t)(b * SEQ + t0)) * HID + h * DH + lane;
  u16* op = obuf + ((size_t)(b * SEQ + t0)) * HID + h * DH + lane;
  float r = Rin[(size_t)gid * 64 + lane];
#pragma unroll
  for (int tt = 0; tt < 64; tt += 8) {
    u16 kr[8];
#pragma unroll
    for (int j = 0; j < 8; j++) kr[j] = kp[(size_t)(tt + j) * HID];
#pragma unroll
    for (int j = 0; j < 8; j++) {
      float bt = __shfl(bet, tt + j);
      float vt = __shfl(vs, tt + j);
      float qt = __shfl(qs, tt + j);
      r = fmaf(r, bt, bf2f(kr[j]) * vt);
      op[(size_t)(tt + j) * HID] = f2bf(qt * r);
    }
  }
}

// ---------------- LayerNorm (row per block) ----------------
__global__ __launch_bounds__(256) void ln_kernel(const u16* __restrict__ y,
                                                 const float* __restrict__ g,
                                                 const float* __restrict__ bt,
                                                 float* __restrict__ out) {
  const int row = blockIdx.x;
  const u16* yr = y + (size_t)row * HID;
  const int t = threadIdx.x;
  ushort4 u = *(const ushort4*)(yr + t * 4);
  float v0 = bf2f(u.x), v1 = bf2f(u.y), v2 = bf2f(u.z), v3 = bf2f(u.w);
  float s  = v0 + v1 + v2 + v3;
  float ss = v0 * v0 + v1 * v1 + v2 * v2 + v3 * v3;
#pragma unroll
  for (int m = 1; m < 64; m <<= 1) { s += __shfl_xor(s, m); ss += __shfl_xor(ss, m); }
  __shared__ float red[8];
  const int wave = t >> 6, lane = t & 63;
  if (lane == 0) { red[wave] = s; red[4 + wave] = ss; }
  __syncthreads();
  float st  = red[0] + red[1] + red[2] + red[3];
  float sst = red[4] + red[5] + red[6] + red[7];
  float mu  = st * (1.f / 1024.f);
  float var = sst * (1.f / 1024.f) - mu * mu;
  float inv = rsqrtf(var + 1e-5f);
  const int c = t * 4;
  float4 o;
  o.x = g[c + 0] * ((v0 - mu) * inv) + bt[c + 0];
  o.y = g[c + 1] * ((v1 - mu) * inv) + bt[c + 1];
  o.z = g[c + 2] * ((v2 - mu) * inv) + bt[c + 2];
  o.w = g[c + 3] * ((v3 - mu) * inv) + bt[c + 3];
  *(float4*)(out + (size_t)row * HID + c) = o;
}

// ---------------- launch ----------------
extern "C" void kernel_launch(void* const* d_in, const int* in_sizes, int n_in,
                              void* d_out, int out_size, void* d_ws, size_t ws_size,
                              hipStream_t stream) {
  const float* x     = (const float*)d_in[0];
  const float* Wq    = (const float*)d_in[1];
  const float* Wk    = (const float*)d_in[2];
  const float* Wv    = (const float*)d_in[3];
  const float* Wbeta = (const float*)d_in[4];
  const float* bbeta = (const float*)d_in[5];
  const float* Wo    = (const float*)d_in[6];
  const float* b_o   = (const float*)d_in[7];
  const float* ln_g  = (const float*)d_in[8];
  const float* ln_b  = (const float*)d_in[9];
  float* out = (float*)d_out;

  char* ws = (char*)d_ws;
  size_t off = 0;
  auto alloc = [&](size_t bytes) {
    char* p = ws + off; off += (bytes + 255) & ~(size_t)255; return p;
  };
  u16* xb   = (u16*)alloc((size_t)M * HID * 2);   // x bf16 (residual for EPI2)
  u16* kbuf = (u16*)alloc((size_t)M * HID * 2);   // k; reused as y after scans
  u16* obuf = (u16*)alloc((size_t)M * HID * 2);
  u16* WkT  = (u16*)alloc((size_t)HID * HID * 2);
  u16* WoT  = (u16*)alloc((size_t)HID * HID * 2);
  u16* WsT  = (u16*)alloc((size_t)128 * HID * 2);
  float* sq_t = (float*)alloc((size_t)64 * SEQ * 4);
  float* sv_t = (float*)alloc((size_t)64 * SEQ * 4);
  float* sb_t = (float*)alloc((size_t)64 * SEQ * 4);
  float* Pbuf = (float*)alloc((size_t)4096 * 4);
  float* Rloc = (float*)alloc((size_t)4096 * 64 * 4);
  float* Rin  = (float*)alloc((size_t)4096 * 64 * 4);
  u16* ybuf = kbuf;  // kbuf dead (as k) after scan_apply

  cast_x_kernel<<<8192, 256, 0, stream>>>((const float4*)x, (uint4*)xb);
  transpose_cast<<<dim3(32, 32, 2), 256, 0, stream>>>(Wk, Wo, WkT, WoT);
  build_wsum<<<512, 256, 0, stream>>>(Wq, Wv, Wbeta, WsT);

  // GEMM1 merged: 128 bm x (8 WkT col-blocks + 1 skinny WsT block) = 1152 blocks
  gemm_bf16<128, 128, 2, 2, 3><<<(M / 128) * 9, 256, 0, stream>>>(
      xb, WkT, WsT, HID, KD, 9, kbuf, nullptr, bbeta, sq_t, sv_t, sb_t);

  scan_chunks<<<1024, 256, 0, stream>>>(kbuf, sv_t, sb_t, Pbuf, Rloc);
  scan_prefix<<<64, 64, 0, stream>>>(Pbuf, Rloc, Rin);
  scan_apply<<<1024, 256, 0, stream>>>(kbuf, sq_t, sv_t, sb_t, Rin, obuf);

  // EPI2: y = bf16(xb + obuf@WoT + b_o), written over kbuf (k is dead now)
  gemm_bf16<128, 128, 2, 2, 2><<<(M / 128) * (HID / 128), 256, 0, stream>>>(
      obuf, WoT, nullptr, HID, KD, HID / 128, ybuf, xb, b_o, nullptr, nullptr, nullptr);

  ln_kernel<<<M, 256, 0, stream>>>(ybuf, ln_g, ln_b, out);
}